// Round 1
// baseline (9289.709 us; speedup 1.0000x reference)
//
#include <hip/hip_runtime.h>
#include <hip/hip_bf16.h>

#define NUM_USER 300000
#define NUM_ITEM 200000
#define NTOT (NUM_USER + NUM_ITEM)
#define D 64
#define RPB 128                         // rows per bucket
#define NB ((NTOT + RPB - 1) / RPB)     // 3907 buckets
#define NBLK 256                        // edge-chunk blocks for hist/scatter

// ---------- phase 1a: per-block bucket histogram (LDS atomics only) ----------

__global__ __launch_bounds__(256) void hist_bucket(
    const int* __restrict__ rows, int* __restrict__ blockhist, int nnz)
{
    __shared__ int h[NB];   // 15.6 KB
    for (int i = threadIdx.x; i < NB; i += 256) h[i] = 0;
    __syncthreads();
    int chunk = (nnz + NBLK - 1) / NBLK;
    int lo = blockIdx.x * chunk;
    int hi = min(lo + chunk, nnz);
    for (int e = lo + threadIdx.x; e < hi; e += 256)
        atomicAdd(&h[rows[e] >> 7], 1);
    __syncthreads();
    for (int i = threadIdx.x; i < NB; i += 256)
        blockhist[blockIdx.x * NB + i] = h[i];
}

// ---------- phase 1b: per-bucket exclusive scan across blocks ----------
// blockhist[b*NB + k] -> exclusive prefix over b; coltotal[k] = total

__global__ __launch_bounds__(256) void colscan(
    int* __restrict__ blockhist, int* __restrict__ coltotal)
{
    int kb = blockIdx.x * 256 + threadIdx.x;
    if (kb >= NB) return;
    int sum = 0;
    for (int b = 0; b < NBLK; b++) {
        int v = blockhist[b * NB + kb];   // 64 lanes -> 256B coalesced
        blockhist[b * NB + kb] = sum;
        sum += v;
    }
    coltotal[kb] = sum;
}

// ---------- phase 1c: exclusive scan of bucket totals (single block) ----------

__global__ __launch_bounds__(256) void bucketscan(
    const int* __restrict__ coltotal, int* __restrict__ bucketbase, int nnz)
{
    __shared__ int s[256];
    int t = threadIdx.x;
    int local[16];
    int sum = 0;
    #pragma unroll
    for (int i = 0; i < 16; i++) {
        int idx = t * 16 + i;
        int c = (idx < NB) ? coltotal[idx] : 0;
        local[i] = sum;       // exclusive within thread
        sum += c;
    }
    s[t] = sum;
    __syncthreads();
    int v = sum;
    for (int off = 1; off < 256; off <<= 1) {
        int add = (t >= off) ? s[t - off] : 0;
        __syncthreads();
        s[t] += add;
        __syncthreads();
    }
    int base = s[t] - v;      // exclusive across block
    #pragma unroll
    for (int i = 0; i < 16; i++) {
        int idx = t * 16 + i;
        if (idx < NB) bucketbase[idx] = base + local[i];
    }
    if (t == 255) bucketbase[NB] = base + sum;   // == nnz
}

// ---------- phase 1d: deterministic scatter into bucket segments ----------
// record = (local_row << 24) | edge_id   (nnz < 2^24, local_row < 128)

__global__ __launch_bounds__(256) void scatter_bucket(
    const int* __restrict__ rows, const int* __restrict__ blockhist,
    const int* __restrict__ bucketbase, int* __restrict__ order, int nnz)
{
    __shared__ int cur[NB];   // 15.6 KB
    for (int i = threadIdx.x; i < NB; i += 256)
        cur[i] = blockhist[blockIdx.x * NB + i] + bucketbase[i];
    __syncthreads();
    int chunk = (nnz + NBLK - 1) / NBLK;
    int lo = blockIdx.x * chunk;
    int hi = min(lo + chunk, nnz);
    for (int e = lo + threadIdx.x; e < hi; e += 256) {
        int r = rows[e];
        int pos = atomicAdd(&cur[r >> 7], 1);     // LDS atomic, fast
        order[pos] = ((r & (RPB - 1)) << 24) | e;
    }
}

// ---------- phase 2: bucket accumulate (LDS f32 atomics) + fused GEMM ----------

__global__ __launch_bounds__(256) void accum_kernel(
    const float* __restrict__ users_emb, const float* __restrict__ items_emb,
    const float* __restrict__ vals, const int* __restrict__ cols,
    const int* __restrict__ bucketbase, const int* __restrict__ order,
    const float* __restrict__ w, float* __restrict__ out)
{
    __shared__ float acc[RPB * D];   // 32 KB, acc[lrow*64 + dim]
    __shared__ float wt[D * 68];     // 17 KB, transposed+padded: wt[col*68 + k]
    int tid = threadIdx.x;

    // load w transposed (w[k*64+col] -> wt[col*68+k])
    for (int i = tid; i < D * D; i += 256) {
        int k = i >> 6, col = i & 63;
        wt[col * 68 + k] = w[i];
    }
    for (int i = tid; i < RPB * D; i += 256) acc[i] = 0.f;
    __syncthreads();

    int kb = blockIdx.x;
    int start = bucketbase[kb];
    int end   = bucketbase[kb + 1];
    int lane = tid & 63;
    int wid  = tid >> 6;

    for (int base = start + wid * 64; base < end; base += 256) {
        int m = end - base;
        int ck = 0; float v = 0.f;
        if (lane < m) {
            int rec  = order[base + lane];        // coalesced
            int e    = rec & 0xFFFFFF;
            int lrow = rec >> 24;
            ck = cols[e] | (lrow << 19);          // col < 2^19, lrow in bits 19..25
            v  = vals[e];
        }
        if (m >= 64) {
            #pragma unroll 8
            for (int j = 0; j < 64; j++) {
                int ckj  = __shfl(ck, j);
                float vj = __shfl(v, j);
                int cj = ckj & 0x7FFFF;
                int lr = ckj >> 19;
                const float* src = (cj < NUM_USER)
                    ? users_emb + (size_t)cj * D
                    : items_emb + (size_t)(cj - NUM_USER) * D;
                atomicAdd(&acc[lr * D + lane], vj * src[lane]);  // ds_add_f32
            }
        } else {
            for (int j = 0; j < m; j++) {
                int ckj  = __shfl(ck, j);
                float vj = __shfl(v, j);
                int cj = ckj & 0x7FFFF;
                int lr = ckj >> 19;
                const float* src = (cj < NUM_USER)
                    ? users_emb + (size_t)cj * D
                    : items_emb + (size_t)(cj - NUM_USER) * D;
                atomicAdd(&acc[lr * D + lane], vj * src[lane]);
            }
        }
    }
    __syncthreads();

    // fused: out_rows = leaky_relu(acc @ w), 128x64 per block
    size_t row0 = (size_t)kb * RPB;
    int col = lane;          // output column
    int quarter = wid;       // rows quarter*32 .. +31
    float res[32];
    #pragma unroll
    for (int rr = 0; rr < 32; rr++) res[rr] = 0.f;
    #pragma unroll
    for (int k4 = 0; k4 < 16; k4++) {
        float4 wv = *(const float4*)&wt[col * 68 + k4 * 4];
        #pragma unroll
        for (int rr = 0; rr < 32; rr++) {
            int row = quarter * 32 + rr;
            float4 av = *(const float4*)&acc[row * D + k4 * 4];  // wave-broadcast
            res[rr] = fmaf(av.x, wv.x, res[rr]);
            res[rr] = fmaf(av.y, wv.y, res[rr]);
            res[rr] = fmaf(av.z, wv.z, res[rr]);
            res[rr] = fmaf(av.w, wv.w, res[rr]);
        }
    }
    #pragma unroll
    for (int rr = 0; rr < 32; rr++) {
        size_t grow = row0 + quarter * 32 + rr;
        if (grow < NTOT) {
            float x = res[rr];
            out[grow * D + col] = x > 0.f ? x : 0.2f * x;
        }
    }
}

extern "C" void kernel_launch(void* const* d_in, const int* in_sizes, int n_in,
                              void* d_out, int out_size, void* d_ws, size_t ws_size,
                              hipStream_t stream) {
    const float* users_emb = (const float*)d_in[0];
    const float* items_emb = (const float*)d_in[1];
    const float* vals      = (const float*)d_in[2];
    const float* w         = (const float*)d_in[3];
    const int*   rows      = (const int*)d_in[4];
    const int*   cols      = (const int*)d_in[5];
    float* out = (float*)d_out;

    int nnz = in_sizes[2];

    // workspace layout (bytes), total 48 MB (same budget as previous version):
    //   blockhist  @ 0        : NBLK*NB ints  (3.8 MB)
    //   coltotal   @ 4 MB     : NB ints       (15.6 KB)
    //   bucketbase @ 4 MB+64K : NB+1 ints     (15.6 KB)
    //   order      @ 8 MB     : nnz ints      (40 MB)
    char* ws = (char*)d_ws;
    int* blockhist  = (int*)(ws);
    int* coltotal   = (int*)(ws + (4ull << 20));
    int* bucketbase = (int*)(ws + (4ull << 20) + (64ull << 10));
    int* order      = (int*)(ws + (8ull << 20));

    hist_bucket<<<NBLK, 256, 0, stream>>>(rows, blockhist, nnz);
    colscan<<<(NB + 255) / 256, 256, 0, stream>>>(blockhist, coltotal);
    bucketscan<<<1, 256, 0, stream>>>(coltotal, bucketbase, nnz);
    scatter_bucket<<<NBLK, 256, 0, stream>>>(rows, blockhist, bucketbase, order, nnz);
    accum_kernel<<<NB, 256, 0, stream>>>(
        users_emb, items_emb, vals, cols, bucketbase, order, w, out);
}

// Round 2
// 4095.148 us; speedup vs baseline: 2.2685x; 2.2685x over previous
//
#include <hip/hip_runtime.h>
#include <hip/hip_bf16.h>

#define NUM_USER 300000
#define NUM_ITEM 200000
#define NTOT (NUM_USER + NUM_ITEM)
#define D 64
#define RPB 128                         // rows per bucket
#define NB ((NTOT + RPB - 1) / RPB)     // 3907 buckets
#define NBLK 256                        // edge-chunk blocks for hist/scatter

// ---------- phase 1a: per-block bucket histogram (LDS atomics only) ----------

__global__ __launch_bounds__(256) void hist_bucket(
    const int* __restrict__ rows, int* __restrict__ blockhist, int nnz)
{
    __shared__ int h[NB];   // 15.6 KB
    for (int i = threadIdx.x; i < NB; i += 256) h[i] = 0;
    __syncthreads();
    int chunk = (nnz + NBLK - 1) / NBLK;
    int lo = blockIdx.x * chunk;
    int hi = min(lo + chunk, nnz);
    for (int e = lo + threadIdx.x; e < hi; e += 256)
        atomicAdd(&h[rows[e] >> 7], 1);
    __syncthreads();
    for (int i = threadIdx.x; i < NB; i += 256)
        blockhist[blockIdx.x * NB + i] = h[i];
}

// ---------- phase 1b: per-bucket exclusive scan across blocks ----------

__global__ __launch_bounds__(256) void colscan(
    int* __restrict__ blockhist, int* __restrict__ coltotal)
{
    int kb = blockIdx.x * 256 + threadIdx.x;
    if (kb >= NB) return;
    int sum = 0;
    for (int b = 0; b < NBLK; b++) {
        int v = blockhist[b * NB + kb];   // coalesced across lanes
        blockhist[b * NB + kb] = sum;
        sum += v;
    }
    coltotal[kb] = sum;
}

// ---------- phase 1c: exclusive scan of bucket totals (single block) ----------

__global__ __launch_bounds__(256) void bucketscan(
    const int* __restrict__ coltotal, int* __restrict__ bucketbase, int nnz)
{
    __shared__ int s[256];
    int t = threadIdx.x;
    int local[16];
    int sum = 0;
    #pragma unroll
    for (int i = 0; i < 16; i++) {
        int idx = t * 16 + i;
        int c = (idx < NB) ? coltotal[idx] : 0;
        local[i] = sum;       // exclusive within thread
        sum += c;
    }
    s[t] = sum;
    __syncthreads();
    int v = sum;
    for (int off = 1; off < 256; off <<= 1) {
        int add = (t >= off) ? s[t - off] : 0;
        __syncthreads();
        s[t] += add;
        __syncthreads();
    }
    int base = s[t] - v;      // exclusive across block
    #pragma unroll
    for (int i = 0; i < 16; i++) {
        int idx = t * 16 + i;
        if (idx < NB) bucketbase[idx] = base + local[i];
    }
    if (t == 255) bucketbase[NB] = base + sum;   // == nnz
}

// ---------- phase 1d: deterministic scatter into bucket segments ----------
// record = (local_row << 24) | edge_id   (nnz < 2^24, local_row < 128)

__global__ __launch_bounds__(256) void scatter_bucket(
    const int* __restrict__ rows, const int* __restrict__ blockhist,
    const int* __restrict__ bucketbase, int* __restrict__ order, int nnz)
{
    __shared__ int cur[NB];   // 15.6 KB
    for (int i = threadIdx.x; i < NB; i += 256)
        cur[i] = blockhist[blockIdx.x * NB + i] + bucketbase[i];
    __syncthreads();
    int chunk = (nnz + NBLK - 1) / NBLK;
    int lo = blockIdx.x * chunk;
    int hi = min(lo + chunk, nnz);
    for (int e = lo + threadIdx.x; e < hi; e += 256) {
        int r = rows[e];
        int pos = atomicAdd(&cur[r >> 7], 1);     // LDS atomic, fast
        order[pos] = ((r & (RPB - 1)) << 24) | e;
    }
}

// ---------- phase 2a: bucket accumulate into LDS, dump agg to out ----------
// Slim on purpose: 32 KB LDS, no GEMM, ~40 VGPRs -> 5 blocks/CU.

__global__ __launch_bounds__(256) void accum_kernel(
    const float* __restrict__ users_emb, const float* __restrict__ items_emb,
    const float* __restrict__ vals, const int* __restrict__ cols,
    const int* __restrict__ bucketbase, const int* __restrict__ order,
    float* __restrict__ out)
{
    __shared__ float acc[RPB * D];   // 32 KB, acc[lrow*64 + dim]
    int tid = threadIdx.x;
    for (int i = tid; i < RPB * D; i += 256) acc[i] = 0.f;
    __syncthreads();

    int kb = blockIdx.x;
    int start = bucketbase[kb];
    int end   = bucketbase[kb + 1];
    int lane = tid & 63;
    int wid  = tid >> 6;

    for (int base = start + wid * 64; base < end; base += 256) {
        int m = end - base;
        int ck = 0; float v = 0.f;
        if (lane < m) {
            int rec  = order[base + lane];        // coalesced
            int e    = rec & 0xFFFFFF;
            int lrow = rec >> 24;
            ck = cols[e] | (lrow << 19);          // col < 2^19, lrow bits 19..25
            v  = vals[e];
        }
        if (m >= 64) {
            #pragma unroll 8
            for (int j = 0; j < 64; j++) {
                int ckj  = __shfl(ck, j);
                float vj = __shfl(v, j);
                int cj = ckj & 0x7FFFF;
                int lr = ckj >> 19;
                const float* src = (cj < NUM_USER)
                    ? users_emb + (size_t)cj * D
                    : items_emb + (size_t)(cj - NUM_USER) * D;
                atomicAdd(&acc[lr * D + lane], vj * src[lane]);  // ds_add_f32
            }
        } else {
            for (int j = 0; j < m; j++) {
                int ckj  = __shfl(ck, j);
                float vj = __shfl(v, j);
                int cj = ckj & 0x7FFFF;
                int lr = ckj >> 19;
                const float* src = (cj < NUM_USER)
                    ? users_emb + (size_t)cj * D
                    : items_emb + (size_t)(cj - NUM_USER) * D;
                atomicAdd(&acc[lr * D + lane], vj * src[lane]);
            }
        }
    }
    __syncthreads();

    // coalesced float4 dump: 2048 float4s per block
    size_t row0 = (size_t)kb * RPB;
    const float4* a4 = (const float4*)acc;
    float4* o4 = (float4*)(out + row0 * D);
    #pragma unroll
    for (int i = tid; i < RPB * D / 4; i += 256) {
        size_t grow = row0 + (i >> 4);
        if (grow < NTOT) o4[i] = a4[i];
    }
}

// ---------- phase 2b: in-place out_row = leaky_relu(agg_row @ w) ----------

__global__ __launch_bounds__(256) void rowgemm_kernel(
    float* __restrict__ out, const float* __restrict__ w, int n)
{
    __shared__ float ws[D * D];   // 16 KB
    __shared__ float as[16 * D];  // 4 KB
    int tid = threadIdx.x;

    const float4* w4 = (const float4*)w;
    float4* ws4 = (float4*)ws;
    #pragma unroll
    for (int i = 0; i < 4; i++) ws4[tid + i * 256] = w4[tid + i * 256];

    size_t row0 = (size_t)blockIdx.x * 16;
    ((float4*)as)[tid] = ((const float4*)(out + row0 * D))[tid];
    __syncthreads();

    int col  = tid & 63;
    int rsub = tid >> 6;
    float res[4];
    #pragma unroll
    for (int rr = 0; rr < 4; rr++) {
        int row = rr * 4 + rsub;
        float acc = 0.f;
        #pragma unroll
        for (int k = 0; k < D; k++) {
            acc = fmaf(as[row * D + k], ws[k * D + col], acc);
        }
        res[rr] = acc > 0.f ? acc : 0.2f * acc;
    }
    #pragma unroll
    for (int rr = 0; rr < 4; rr++) {
        int row = rr * 4 + rsub;
        out[(row0 + row) * D + col] = res[rr];
    }
}

extern "C" void kernel_launch(void* const* d_in, const int* in_sizes, int n_in,
                              void* d_out, int out_size, void* d_ws, size_t ws_size,
                              hipStream_t stream) {
    const float* users_emb = (const float*)d_in[0];
    const float* items_emb = (const float*)d_in[1];
    const float* vals      = (const float*)d_in[2];
    const float* w         = (const float*)d_in[3];
    const int*   rows      = (const int*)d_in[4];
    const int*   cols      = (const int*)d_in[5];
    float* out = (float*)d_out;

    int nnz = in_sizes[2];
    int n   = NTOT;

    // workspace layout (bytes), total ~44 MB (within proven 48 MB budget):
    //   blockhist  @ 0        : NBLK*NB ints  (3.8 MB)
    //   coltotal   @ 4 MB     : NB ints       (15.6 KB)
    //   bucketbase @ 4 MB+64K : NB+1 ints     (15.6 KB)
    //   order      @ 8 MB     : nnz ints      (40 MB)
    char* ws = (char*)d_ws;
    int* blockhist  = (int*)(ws);
    int* coltotal   = (int*)(ws + (4ull << 20));
    int* bucketbase = (int*)(ws + (4ull << 20) + (64ull << 10));
    int* order      = (int*)(ws + (8ull << 20));

    hist_bucket<<<NBLK, 256, 0, stream>>>(rows, blockhist, nnz);
    colscan<<<(NB + 255) / 256, 256, 0, stream>>>(blockhist, coltotal);
    bucketscan<<<1, 256, 0, stream>>>(coltotal, bucketbase, nnz);
    scatter_bucket<<<NBLK, 256, 0, stream>>>(rows, blockhist, bucketbase, order, nnz);
    accum_kernel<<<NB, 256, 0, stream>>>(
        users_emb, items_emb, vals, cols, bucketbase, order, out);
    rowgemm_kernel<<<n / 16, 256, 0, stream>>>(out, w, n);
}